// Round 1
// baseline (1105.766 us; speedup 1.0000x reference)
//
#include <hip/hip_runtime.h>
#include <hip/hip_bf16.h>

#define N_NODES 50000
#define N_EDGES 800000
#define ETOT    (N_EDGES + N_NODES)
#define NB      64
#define IN_C    128
#define HID     64
#define HEADS   4
#define F1      (HEADS * HID)   /* 256 */
#define NEG     0.2f

__device__ __forceinline__ float lrelu(float x) { return x >= 0.f ? x : NEG * x; }

// ---------------- CSR build ----------------
__global__ void deg_kernel(const int* __restrict__ ei, int* __restrict__ deg) {
    int e = blockIdx.x * 256 + threadIdx.x;
    if (e >= ETOT) return;
    int d = (e < N_EDGES) ? ei[N_EDGES + e] : (e - N_EDGES);
    atomicAdd(&deg[d], 1);
}

__global__ void scan_kernel(int* __restrict__ deg, int* __restrict__ off) {
    __shared__ int sh[1024];
    int t = threadIdx.x;
    const int CH = (N_NODES + 1023) / 1024;  // 49
    int start = t * CH;
    int end   = min(start + CH, N_NODES);
    int s = 0;
    for (int i = start; i < end; ++i) s += deg[i];
    sh[t] = s;
    __syncthreads();
    for (int o = 1; o < 1024; o <<= 1) {
        int v = (t >= o) ? sh[t - o] : 0;
        __syncthreads();
        sh[t] += v;
        __syncthreads();
    }
    int base = (t == 0) ? 0 : sh[t - 1];
    for (int i = start; i < end; ++i) { off[i] = base; base += deg[i]; }
    if (t == 1023) off[N_NODES] = sh[1023];
    __syncthreads();
    for (int i = start; i < end; ++i) deg[i] = 0;  // reuse as cursor
}

__global__ void scatter_kernel(const int* __restrict__ ei, const int* __restrict__ off,
                               int* __restrict__ cursor, int* __restrict__ esrc) {
    int e = blockIdx.x * 256 + threadIdx.x;
    if (e >= ETOT) return;
    int s, d;
    if (e < N_EDGES) { s = ei[e]; d = ei[N_EDGES + e]; }
    else             { s = d = e - N_EDGES; }
    int pos = off[d] + atomicAdd(&cursor[d], 1);
    esrc[pos] = s;
}

// ---------------- f32 tiled GEMM: C[N,256] = A[N,K] @ W[K,256] ----------------
__global__ __launch_bounds__(256) void gemm_kernel(const float* __restrict__ A,
                                                   const float* __restrict__ W,
                                                   float* __restrict__ C,
                                                   int nrows, int K) {
    __shared__ float As[64][33];
    __shared__ float Ws[32][64];
    int t  = threadIdx.x;
    int tx = t % 16, ty = t / 16;
    int row0 = blockIdx.x * 64;
    int col0 = blockIdx.y * 64;
    float acc[4][4] = {};
    for (int k0 = 0; k0 < K; k0 += 32) {
        int ka = t % 32;
        for (int r = t / 32; r < 64; r += 8) {
            int gr = row0 + r;
            As[r][ka] = (gr < nrows) ? A[(size_t)gr * K + k0 + ka] : 0.f;
        }
        int nc = t % 64;
        for (int k = t / 64; k < 32; k += 4) {
            Ws[k][nc] = W[(size_t)(k0 + k) * F1 + col0 + nc];
        }
        __syncthreads();
        #pragma unroll
        for (int k = 0; k < 32; ++k) {
            float a[4], b[4];
            #pragma unroll
            for (int i = 0; i < 4; ++i) a[i] = As[ty * 4 + i][k];
            #pragma unroll
            for (int j = 0; j < 4; ++j) b[j] = Ws[k][tx * 4 + j];
            #pragma unroll
            for (int i = 0; i < 4; ++i)
                #pragma unroll
                for (int j = 0; j < 4; ++j) acc[i][j] += a[i] * b[j];
        }
        __syncthreads();
    }
    for (int i = 0; i < 4; ++i) {
        int gr = row0 + ty * 4 + i;
        if (gr < nrows)
            for (int j = 0; j < 4; ++j)
                C[(size_t)gr * F1 + col0 + tx * 4 + j] = acc[i][j];
    }
}

// ---------------- per-node attention coefficients ----------------
__global__ void alpha_kernel(const float* __restrict__ h,
                             const float* __restrict__ a_s,
                             const float* __restrict__ a_d,
                             float* __restrict__ asrc, float* __restrict__ adst) {
    int wid  = threadIdx.x >> 6;
    int lane = threadIdx.x & 63;
    int n = blockIdx.x * 4 + wid;
    if (n >= N_NODES) return;
    const float* hn = h + (size_t)n * F1;
    float ps[HEADS], pd[HEADS];
    #pragma unroll
    for (int hh = 0; hh < HEADS; ++hh) {
        float v = hn[hh * 64 + lane];
        ps[hh] = v * a_s[hh * 64 + lane];
        pd[hh] = v * a_d[hh * 64 + lane];
    }
    #pragma unroll
    for (int o = 32; o; o >>= 1) {
        #pragma unroll
        for (int hh = 0; hh < HEADS; ++hh) {
            ps[hh] += __shfl_xor(ps[hh], o);
            pd[hh] += __shfl_xor(pd[hh], o);
        }
    }
    if (lane == 0) {
        #pragma unroll
        for (int hh = 0; hh < HEADS; ++hh) {
            asrc[n * HEADS + hh] = ps[hh];
            adst[n * HEADS + hh] = pd[hh];
        }
    }
}

// ---------------- segment softmax + aggregation (one wave per dst node) ----------------
template <int LAYER>
__global__ void agg_kernel(const float* __restrict__ h,
                           const float* __restrict__ asrc,
                           const float* __restrict__ adst,
                           const int* __restrict__ off,
                           const int* __restrict__ esrc,
                           const float* __restrict__ bias,
                           float* __restrict__ out) {
    int d    = blockIdx.x;
    int lane = threadIdx.x;  // 64 threads = 1 wave
    int e0 = off[d], e1 = off[d + 1];
    float ad0 = adst[d * 4 + 0], ad1 = adst[d * 4 + 1];
    float ad2 = adst[d * 4 + 2], ad3 = adst[d * 4 + 3];
    // pass A: softmax denominator per head
    float w0 = 0.f, w1 = 0.f, w2 = 0.f, w3 = 0.f;
    for (int i = e0 + lane; i < e1; i += 64) {
        int s = esrc[i];
        float4 as = *(const float4*)(asrc + (size_t)s * 4);
        w0 += __expf(lrelu(as.x + ad0));
        w1 += __expf(lrelu(as.y + ad1));
        w2 += __expf(lrelu(as.z + ad2));
        w3 += __expf(lrelu(as.w + ad3));
    }
    #pragma unroll
    for (int o = 32; o; o >>= 1) {
        w0 += __shfl_xor(w0, o);
        w1 += __shfl_xor(w1, o);
        w2 += __shfl_xor(w2, o);
        w3 += __shfl_xor(w3, o);
    }
    float r0 = 1.f / fmaxf(w0, 1e-16f);
    float r1 = 1.f / fmaxf(w1, 1e-16f);
    float r2 = 1.f / fmaxf(w2, 1e-16f);
    float r3 = 1.f / fmaxf(w3, 1e-16f);
    // pass B: weighted gather-accumulate; lane owns channel `lane` for each head
    float acc0 = 0.f, acc1 = 0.f, acc2 = 0.f, acc3 = 0.f;
    for (int i = e0; i < e1; ++i) {
        int s = esrc[i];
        float4 as = *(const float4*)(asrc + (size_t)s * 4);
        float c0 = __expf(lrelu(as.x + ad0)) * r0;
        float c1 = __expf(lrelu(as.y + ad1)) * r1;
        float c2 = __expf(lrelu(as.z + ad2)) * r2;
        float c3 = __expf(lrelu(as.w + ad3)) * r3;
        const float* hs = h + (size_t)s * F1;
        acc0 += c0 * hs[lane];
        acc1 += c1 * hs[64 + lane];
        acc2 += c2 * hs[128 + lane];
        acc3 += c3 * hs[192 + lane];
    }
    if (LAYER == 1) {
        out[(size_t)d * F1 + lane]       = fmaxf(acc0 + bias[lane], 0.f);
        out[(size_t)d * F1 + 64 + lane]  = fmaxf(acc1 + bias[64 + lane], 0.f);
        out[(size_t)d * F1 + 128 + lane] = fmaxf(acc2 + bias[128 + lane], 0.f);
        out[(size_t)d * F1 + 192 + lane] = fmaxf(acc3 + bias[192 + lane], 0.f);
    } else {
        out[(size_t)d * HID + lane] = 0.25f * (acc0 + acc1 + acc2 + acc3) + bias[lane];
    }
}

// ---------------- global mean pool ----------------
__global__ void pool_kernel(const float* __restrict__ h2,
                            const int* __restrict__ batch,
                            float* __restrict__ psum, float* __restrict__ pcnt) {
    int n = blockIdx.x;
    int lane = threadIdx.x;  // 64
    int b = batch[n];
    atomicAdd(&psum[b * HID + lane], h2[(size_t)n * HID + lane]);
    if (lane == 0) atomicAdd(&pcnt[b], 1.0f);
}

// ---------------- graph MLP ----------------
__global__ void mlp_kernel(const float* __restrict__ psum, const float* __restrict__ pcnt,
                           const float* __restrict__ Wm1, const float* __restrict__ bm1,
                           const float* __restrict__ Wm2, const float* __restrict__ bm2,
                           float* __restrict__ out) {
    __shared__ float P[NB][HID];
    __shared__ float Hh[NB][HID];
    int t = threadIdx.x;
    for (int i = t; i < NB * HID; i += 256) {
        int b = i / HID;
        P[b][i % HID] = psum[i] / fmaxf(pcnt[b], 1.0f);
    }
    __syncthreads();
    for (int i = t; i < NB * HID; i += 256) {
        int b = i / HID, c = i % HID;
        float s = bm1[c];
        for (int k = 0; k < HID; ++k) s += P[b][k] * Wm1[k * HID + c];
        Hh[b][c] = fmaxf(s, 0.f);
    }
    __syncthreads();
    if (t < NB) {
        float s = bm2[0];
        for (int k = 0; k < HID; ++k) s += Hh[t][k] * Wm2[k];
        out[t] = s;
    }
}

extern "C" void kernel_launch(void* const* d_in, const int* in_sizes, int n_in,
                              void* d_out, int out_size, void* d_ws, size_t ws_size,
                              hipStream_t stream) {
    const float* x   = (const float*)d_in[0];
    const int*   ei  = (const int*)d_in[1];
    const int*   bat = (const int*)d_in[2];
    const float* W1  = (const float*)d_in[3];
    const float* as1 = (const float*)d_in[4];
    const float* ad1 = (const float*)d_in[5];
    const float* b1  = (const float*)d_in[6];
    const float* W2  = (const float*)d_in[7];
    const float* as2 = (const float*)d_in[8];
    const float* ad2 = (const float*)d_in[9];
    const float* b2  = (const float*)d_in[10];
    const float* Wm1 = (const float*)d_in[11];
    const float* bm1 = (const float*)d_in[12];
    const float* Wm2 = (const float*)d_in[13];
    const float* bm2 = (const float*)d_in[14];
    float* out = (float*)d_out;

    char* ws = (char*)d_ws;
    size_t cursor = 0;
    auto alloc = [&](size_t bytes) {
        void* p = ws + cursor;
        cursor += (bytes + 511) & ~(size_t)511;
        return p;
    };
    int*   deg  = (int*)alloc((size_t)N_NODES * 4);
    int*   off  = (int*)alloc((size_t)(N_NODES + 1) * 4);
    int*   esrc = (int*)alloc((size_t)ETOT * 4);
    float* bufH = (float*)alloc((size_t)N_NODES * F1 * 4);
    float* bufO = (float*)alloc((size_t)N_NODES * F1 * 4);
    float* asrc = (float*)alloc((size_t)N_NODES * HEADS * 4);
    float* adst = (float*)alloc((size_t)N_NODES * HEADS * 4);
    float* psum = (float*)alloc((size_t)NB * HID * 4);
    float* pcnt = (float*)alloc((size_t)NB * 4);

    hipMemsetAsync(deg, 0, (size_t)N_NODES * 4, stream);
    hipMemsetAsync(psum, 0, (size_t)NB * HID * 4, stream);
    hipMemsetAsync(pcnt, 0, (size_t)NB * 4, stream);

    deg_kernel<<<(ETOT + 255) / 256, 256, 0, stream>>>(ei, deg);
    scan_kernel<<<1, 1024, 0, stream>>>(deg, off);
    scatter_kernel<<<(ETOT + 255) / 256, 256, 0, stream>>>(ei, off, deg, esrc);

    // layer 1
    gemm_kernel<<<dim3((N_NODES + 63) / 64, 4), 256, 0, stream>>>(x, W1, bufH, N_NODES, IN_C);
    alpha_kernel<<<(N_NODES + 3) / 4, 256, 0, stream>>>(bufH, as1, ad1, asrc, adst);
    agg_kernel<1><<<N_NODES, 64, 0, stream>>>(bufH, asrc, adst, off, esrc, b1, bufO);

    // layer 2
    gemm_kernel<<<dim3((N_NODES + 63) / 64, 4), 256, 0, stream>>>(bufO, W2, bufH, N_NODES, F1);
    alpha_kernel<<<(N_NODES + 3) / 4, 256, 0, stream>>>(bufH, as2, ad2, asrc, adst);
    agg_kernel<2><<<N_NODES, 64, 0, stream>>>(bufH, asrc, adst, off, esrc, b2, bufO);

    // pool + MLP
    pool_kernel<<<N_NODES, 64, 0, stream>>>(bufO, bat, psum, pcnt);
    mlp_kernel<<<1, 256, 0, stream>>>(psum, pcnt, Wm1, bm1, Wm2, bm2, out);
}

// Round 2
// 766.123 us; speedup vs baseline: 1.4433x; 1.4433x over previous
//
#include <hip/hip_runtime.h>
#include <hip/hip_bf16.h>

#define N_NODES 50000
#define N_EDGES 800000
#define ETOT    (N_EDGES + N_NODES)
#define NB      64
#define IN_C    128
#define HID     64
#define HEADS   4
#define F1      (HEADS * HID)   /* 256 */
#define NEG     0.2f

__device__ __forceinline__ float lrelu(float x) { return x >= 0.f ? x : NEG * x; }

// ---------------- CSR build ----------------
__global__ void deg_kernel(const int* __restrict__ ei, int* __restrict__ deg) {
    int e = blockIdx.x * 256 + threadIdx.x;
    if (e >= ETOT) return;
    int d = (e < N_EDGES) ? ei[N_EDGES + e] : (e - N_EDGES);
    atomicAdd(&deg[d], 1);
}

__global__ void scan_kernel(int* __restrict__ deg, int* __restrict__ off) {
    __shared__ int sh[1024];
    int t = threadIdx.x;
    const int CH = (N_NODES + 1023) / 1024;  // 49
    int start = t * CH;
    int end   = min(start + CH, N_NODES);
    int s = 0;
    for (int i = start; i < end; ++i) s += deg[i];
    sh[t] = s;
    __syncthreads();
    for (int o = 1; o < 1024; o <<= 1) {
        int v = (t >= o) ? sh[t - o] : 0;
        __syncthreads();
        sh[t] += v;
        __syncthreads();
    }
    int base = (t == 0) ? 0 : sh[t - 1];
    for (int i = start; i < end; ++i) { off[i] = base; base += deg[i]; }
    if (t == 1023) off[N_NODES] = sh[1023];
    __syncthreads();
    for (int i = start; i < end; ++i) deg[i] = 0;  // reuse as cursor
}

__global__ void scatter_kernel(const int* __restrict__ ei, const int* __restrict__ off,
                               int* __restrict__ cursor, int* __restrict__ esrc) {
    int e = blockIdx.x * 256 + threadIdx.x;
    if (e >= ETOT) return;
    int s, d;
    if (e < N_EDGES) { s = ei[e]; d = ei[N_EDGES + e]; }
    else             { s = d = e - N_EDGES; }
    int pos = off[d] + atomicAdd(&cursor[d], 1);
    esrc[pos] = s;
}

// ---------------- f32 tiled GEMM: C[N,256] = A[N,K] @ W[K,256] ----------------
__global__ __launch_bounds__(256) void gemm_kernel(const float* __restrict__ A,
                                                   const float* __restrict__ W,
                                                   float* __restrict__ C,
                                                   int nrows, int K) {
    __shared__ float As[64][33];
    __shared__ float Ws[32][64];
    int t  = threadIdx.x;
    int tx = t % 16, ty = t / 16;
    int row0 = blockIdx.x * 64;
    int col0 = blockIdx.y * 64;
    float acc[4][4] = {};
    for (int k0 = 0; k0 < K; k0 += 32) {
        int ka = t % 32;
        for (int r = t / 32; r < 64; r += 8) {
            int gr = row0 + r;
            As[r][ka] = (gr < nrows) ? A[(size_t)gr * K + k0 + ka] : 0.f;
        }
        int nc = t % 64;
        for (int k = t / 64; k < 32; k += 4) {
            Ws[k][nc] = W[(size_t)(k0 + k) * F1 + col0 + nc];
        }
        __syncthreads();
        #pragma unroll
        for (int k = 0; k < 32; ++k) {
            float a[4], b[4];
            #pragma unroll
            for (int i = 0; i < 4; ++i) a[i] = As[ty * 4 + i][k];
            #pragma unroll
            for (int j = 0; j < 4; ++j) b[j] = Ws[k][tx * 4 + j];
            #pragma unroll
            for (int i = 0; i < 4; ++i)
                #pragma unroll
                for (int j = 0; j < 4; ++j) acc[i][j] += a[i] * b[j];
        }
        __syncthreads();
    }
    for (int i = 0; i < 4; ++i) {
        int gr = row0 + ty * 4 + i;
        if (gr < nrows)
            for (int j = 0; j < 4; ++j)
                C[(size_t)gr * F1 + col0 + tx * 4 + j] = acc[i][j];
    }
}

// ---------------- per-node attention coefficients ----------------
__global__ void alpha_kernel(const float* __restrict__ h,
                             const float* __restrict__ a_s,
                             const float* __restrict__ a_d,
                             float* __restrict__ asrc, float* __restrict__ adst) {
    int wid  = threadIdx.x >> 6;
    int lane = threadIdx.x & 63;
    int n = blockIdx.x * 4 + wid;
    if (n >= N_NODES) return;
    const float* hn = h + (size_t)n * F1;
    float ps[HEADS], pd[HEADS];
    #pragma unroll
    for (int hh = 0; hh < HEADS; ++hh) {
        float v = hn[hh * 64 + lane];
        ps[hh] = v * a_s[hh * 64 + lane];
        pd[hh] = v * a_d[hh * 64 + lane];
    }
    #pragma unroll
    for (int o = 32; o; o >>= 1) {
        #pragma unroll
        for (int hh = 0; hh < HEADS; ++hh) {
            ps[hh] += __shfl_xor(ps[hh], o);
            pd[hh] += __shfl_xor(pd[hh], o);
        }
    }
    if (lane == 0) {
        #pragma unroll
        for (int hh = 0; hh < HEADS; ++hh) {
            asrc[n * HEADS + hh] = ps[hh];
            adst[n * HEADS + hh] = pd[hh];
        }
    }
}

// ---------------- segment softmax + aggregation (one wave per dst node) ----------------
template <int LAYER>
__global__ void agg_kernel(const float* __restrict__ h,
                           const float* __restrict__ asrc,
                           const float* __restrict__ adst,
                           const int* __restrict__ off,
                           const int* __restrict__ esrc,
                           const float* __restrict__ bias,
                           float* __restrict__ out) {
    int d    = blockIdx.x;
    int lane = threadIdx.x;  // 64 threads = 1 wave
    int e0 = off[d], e1 = off[d + 1];
    float ad0 = adst[d * 4 + 0], ad1 = adst[d * 4 + 1];
    float ad2 = adst[d * 4 + 2], ad3 = adst[d * 4 + 3];
    // pass A: softmax denominator per head
    float w0 = 0.f, w1 = 0.f, w2 = 0.f, w3 = 0.f;
    for (int i = e0 + lane; i < e1; i += 64) {
        int s = esrc[i];
        float4 as = *(const float4*)(asrc + (size_t)s * 4);
        w0 += __expf(lrelu(as.x + ad0));
        w1 += __expf(lrelu(as.y + ad1));
        w2 += __expf(lrelu(as.z + ad2));
        w3 += __expf(lrelu(as.w + ad3));
    }
    #pragma unroll
    for (int o = 32; o; o >>= 1) {
        w0 += __shfl_xor(w0, o);
        w1 += __shfl_xor(w1, o);
        w2 += __shfl_xor(w2, o);
        w3 += __shfl_xor(w3, o);
    }
    float r0 = 1.f / fmaxf(w0, 1e-16f);
    float r1 = 1.f / fmaxf(w1, 1e-16f);
    float r2 = 1.f / fmaxf(w2, 1e-16f);
    float r3 = 1.f / fmaxf(w3, 1e-16f);
    // pass B: weighted gather-accumulate; lane owns channel `lane` for each head
    float acc0 = 0.f, acc1 = 0.f, acc2 = 0.f, acc3 = 0.f;
    for (int i = e0; i < e1; ++i) {
        int s = esrc[i];
        float4 as = *(const float4*)(asrc + (size_t)s * 4);
        float c0 = __expf(lrelu(as.x + ad0)) * r0;
        float c1 = __expf(lrelu(as.y + ad1)) * r1;
        float c2 = __expf(lrelu(as.z + ad2)) * r2;
        float c3 = __expf(lrelu(as.w + ad3)) * r3;
        const float* hs = h + (size_t)s * F1;
        acc0 += c0 * hs[lane];
        acc1 += c1 * hs[64 + lane];
        acc2 += c2 * hs[128 + lane];
        acc3 += c3 * hs[192 + lane];
    }
    if (LAYER == 1) {
        out[(size_t)d * F1 + lane]       = fmaxf(acc0 + bias[lane], 0.f);
        out[(size_t)d * F1 + 64 + lane]  = fmaxf(acc1 + bias[64 + lane], 0.f);
        out[(size_t)d * F1 + 128 + lane] = fmaxf(acc2 + bias[128 + lane], 0.f);
        out[(size_t)d * F1 + 192 + lane] = fmaxf(acc3 + bias[192 + lane], 0.f);
    } else {
        out[(size_t)d * HID + lane] = 0.25f * (acc0 + acc1 + acc2 + acc3) + bias[lane];
    }
}

// ---------------- global mean pool: one block per graph, batch is sorted ----------------
__device__ __forceinline__ int lowerb(const int* __restrict__ a, int n, int v) {
    int lo = 0, hi = n;
    while (lo < hi) { int m = (lo + hi) >> 1; if (a[m] < v) lo = m + 1; else hi = m; }
    return lo;
}

__global__ void pool2_kernel(const float* __restrict__ h2,
                             const int* __restrict__ batch,
                             float* __restrict__ pooled) {
    __shared__ float sh[4][HID];
    int b = blockIdx.x;
    int t = threadIdx.x, w = t >> 6, c = t & 63;
    int lo = lowerb(batch, N_NODES, b);
    int hi = lowerb(batch, N_NODES, b + 1);
    float s = 0.f;
    for (int n = lo + w; n < hi; n += 4) s += h2[(size_t)n * HID + c];
    sh[w][c] = s;
    __syncthreads();
    if (w == 0) {
        float tot = sh[0][c] + sh[1][c] + sh[2][c] + sh[3][c];
        pooled[b * HID + c] = tot / fmaxf((float)(hi - lo), 1.f);
    }
}

// ---------------- graph MLP ----------------
__global__ void mlp_kernel(const float* __restrict__ pooled,
                           const float* __restrict__ Wm1, const float* __restrict__ bm1,
                           const float* __restrict__ Wm2, const float* __restrict__ bm2,
                           float* __restrict__ out) {
    __shared__ float P[NB][HID];
    __shared__ float Hh[NB][HID];
    int t = threadIdx.x;
    for (int i = t; i < NB * HID; i += 256) P[i / HID][i % HID] = pooled[i];
    __syncthreads();
    for (int i = t; i < NB * HID; i += 256) {
        int b = i / HID, c = i % HID;
        float s = bm1[c];
        for (int k = 0; k < HID; ++k) s += P[b][k] * Wm1[k * HID + c];
        Hh[b][c] = fmaxf(s, 0.f);
    }
    __syncthreads();
    if (t < NB) {
        float s = bm2[0];
        for (int k = 0; k < HID; ++k) s += Hh[t][k] * Wm2[k];
        out[t] = s;
    }
}

extern "C" void kernel_launch(void* const* d_in, const int* in_sizes, int n_in,
                              void* d_out, int out_size, void* d_ws, size_t ws_size,
                              hipStream_t stream) {
    const float* x   = (const float*)d_in[0];
    const int*   ei  = (const int*)d_in[1];
    const int*   bat = (const int*)d_in[2];
    const float* W1  = (const float*)d_in[3];
    const float* as1 = (const float*)d_in[4];
    const float* ad1 = (const float*)d_in[5];
    const float* b1  = (const float*)d_in[6];
    const float* W2  = (const float*)d_in[7];
    const float* as2 = (const float*)d_in[8];
    const float* ad2 = (const float*)d_in[9];
    const float* b2  = (const float*)d_in[10];
    const float* Wm1 = (const float*)d_in[11];
    const float* bm1 = (const float*)d_in[12];
    const float* Wm2 = (const float*)d_in[13];
    const float* bm2 = (const float*)d_in[14];
    float* out = (float*)d_out;

    char* ws = (char*)d_ws;
    size_t cursor = 0;
    auto alloc = [&](size_t bytes) {
        void* p = ws + cursor;
        cursor += (bytes + 511) & ~(size_t)511;
        return p;
    };
    int*   deg    = (int*)alloc((size_t)N_NODES * 4);
    int*   off    = (int*)alloc((size_t)(N_NODES + 1) * 4);
    int*   esrc   = (int*)alloc((size_t)ETOT * 4);
    float* bufH   = (float*)alloc((size_t)N_NODES * F1 * 4);
    float* bufO   = (float*)alloc((size_t)N_NODES * F1 * 4);
    float* asrc   = (float*)alloc((size_t)N_NODES * HEADS * 4);
    float* adst   = (float*)alloc((size_t)N_NODES * HEADS * 4);
    float* pooled = (float*)alloc((size_t)NB * HID * 4);

    hipMemsetAsync(deg, 0, (size_t)N_NODES * 4, stream);

    deg_kernel<<<(ETOT + 255) / 256, 256, 0, stream>>>(ei, deg);
    scan_kernel<<<1, 1024, 0, stream>>>(deg, off);
    scatter_kernel<<<(ETOT + 255) / 256, 256, 0, stream>>>(ei, off, deg, esrc);

    // layer 1
    gemm_kernel<<<dim3((N_NODES + 63) / 64, 4), 256, 0, stream>>>(x, W1, bufH, N_NODES, IN_C);
    alpha_kernel<<<(N_NODES + 3) / 4, 256, 0, stream>>>(bufH, as1, ad1, asrc, adst);
    agg_kernel<1><<<N_NODES, 64, 0, stream>>>(bufH, asrc, adst, off, esrc, b1, bufO);

    // layer 2
    gemm_kernel<<<dim3((N_NODES + 63) / 64, 4), 256, 0, stream>>>(bufO, W2, bufH, N_NODES, F1);
    alpha_kernel<<<(N_NODES + 3) / 4, 256, 0, stream>>>(bufH, as2, ad2, asrc, adst);
    agg_kernel<2><<<N_NODES, 64, 0, stream>>>(bufH, asrc, adst, off, esrc, b2, bufO);

    // pool + MLP (batch is sorted -> binary-search ranges, no atomics)
    pool2_kernel<<<NB, 256, 0, stream>>>(bufO, bat, pooled);
    mlp_kernel<<<1, 256, 0, stream>>>(pooled, Wm1, bm1, Wm2, bm2, out);
}

// Round 3
// 630.425 us; speedup vs baseline: 1.7540x; 1.2152x over previous
//
#include <hip/hip_runtime.h>
#include <hip/hip_bf16.h>

#define N_NODES 50000
#define N_EDGES 800000
#define ETOT    (N_EDGES + N_NODES)
#define NB      64
#define IN_C    128
#define HID     64
#define HEADS   4
#define F1      (HEADS * HID)   /* 256 */
#define NEG     0.2f

typedef __attribute__((ext_vector_type(8))) short  short8v;
typedef __attribute__((ext_vector_type(4))) float  float4v;

__device__ __forceinline__ float lrelu(float x) { return x >= 0.f ? x : NEG * x; }

// round-to-nearest-even f32 -> bf16 bits
__device__ __forceinline__ unsigned short f2bf(float f) {
    unsigned u = __float_as_uint(f);
    u += 0x7FFFu + ((u >> 16) & 1u);
    return (unsigned short)(u >> 16);
}
__device__ __forceinline__ float bf2f(unsigned short h) {
    return __uint_as_float(((unsigned)h) << 16);
}

// ---------------- CSR build ----------------
__global__ void deg_kernel(const int* __restrict__ ei, int* __restrict__ deg) {
    int e = blockIdx.x * 256 + threadIdx.x;
    if (e >= ETOT) return;
    int d = (e < N_EDGES) ? ei[N_EDGES + e] : (e - N_EDGES);
    atomicAdd(&deg[d], 1);
}

__global__ void scan_kernel(int* __restrict__ deg, int* __restrict__ off) {
    __shared__ int sh[1024];
    int t = threadIdx.x;
    const int CH = (N_NODES + 1023) / 1024;
    int start = t * CH;
    int end   = min(start + CH, N_NODES);
    int s = 0;
    for (int i = start; i < end; ++i) s += deg[i];
    sh[t] = s;
    __syncthreads();
    for (int o = 1; o < 1024; o <<= 1) {
        int v = (t >= o) ? sh[t - o] : 0;
        __syncthreads();
        sh[t] += v;
        __syncthreads();
    }
    int base = (t == 0) ? 0 : sh[t - 1];
    for (int i = start; i < end; ++i) { off[i] = base; base += deg[i]; }
    if (t == 1023) off[N_NODES] = sh[1023];
    __syncthreads();
    for (int i = start; i < end; ++i) deg[i] = 0;  // reuse as cursor
}

__global__ void scatter_kernel(const int* __restrict__ ei, const int* __restrict__ off,
                               int* __restrict__ cursor, int* __restrict__ esrc) {
    int e = blockIdx.x * 256 + threadIdx.x;
    if (e >= ETOT) return;
    int s, d;
    if (e < N_EDGES) { s = ei[e]; d = ei[N_EDGES + e]; }
    else             { s = d = e - N_EDGES; }
    int pos = off[d] + atomicAdd(&cursor[d], 1);
    esrc[pos] = s;
}

// ---------------- W [K][256] f32 -> transposed split bf16 Wt[256][K] hi/lo ----------------
__global__ void convw_kernel(const float* __restrict__ W,
                             unsigned short* __restrict__ Wth,
                             unsigned short* __restrict__ Wtl, int K) {
    int i = blockIdx.x * 256 + threadIdx.x;
    if (i >= K * 256) return;
    int k = i >> 8, n = i & 255;
    float v = W[i];
    unsigned short h = f2bf(v);
    Wth[n * K + k] = h;
    Wtl[n * K + k] = f2bf(v - bf2f(h));
}

// ---------------- split-bf16 MFMA GEMM: C[M,256] = A[M,K] @ W[K,256] ----------------
// A source: f32 (SPLIT_A=true, split during staging) or pre-split bf16 hi/lo.
// W source: pre-transposed split bf16 Wt[256][K].
// 3-product split: C ≈ Ah*Bh + Ah*Bl + Al*Bh  (residual ~2^-17 relative)
template <bool SPLIT_A>
__global__ __launch_bounds__(256) void gemm_mfma(const float* __restrict__ Af32,
                                                 const unsigned short* __restrict__ Ahg,
                                                 const unsigned short* __restrict__ Alg,
                                                 const unsigned short* __restrict__ Wth,
                                                 const unsigned short* __restrict__ Wtl,
                                                 float* __restrict__ C, int M, int K) {
    __shared__ unsigned short Ah[64][40], Al[64][40];    // 32 + 8 pad -> 80B row stride
    __shared__ unsigned short Bh[256][40], Bl[256][40];
    int t  = threadIdx.x;
    int m0 = blockIdx.x * 64;
    int w  = t >> 6, l = t & 63;
    int lr = l & 15, lk = (l >> 4) * 8;

    float4v acc[4][4];
    #pragma unroll
    for (int mf = 0; mf < 4; ++mf)
        #pragma unroll
        for (int nf = 0; nf < 4; ++nf)
            acc[mf][nf] = (float4v){0.f, 0.f, 0.f, 0.f};

    for (int k0 = 0; k0 < K; k0 += 32) {
        // ---- stage A tile (64 x 32) ----
        if (SPLIT_A) {
            #pragma unroll
            for (int p = 0; p < 2; ++p) {
                int idx = t + p * 256;         // 0..511 float4 chunks
                int r = idx >> 3, c4 = (idx & 7) * 4;
                int gr = m0 + r;
                float4 v = make_float4(0.f, 0.f, 0.f, 0.f);
                if (gr < M) v = *(const float4*)&Af32[(size_t)gr * K + k0 + c4];
                ushort4 hi, lo;
                hi.x = f2bf(v.x); lo.x = f2bf(v.x - bf2f(hi.x));
                hi.y = f2bf(v.y); lo.y = f2bf(v.y - bf2f(hi.y));
                hi.z = f2bf(v.z); lo.z = f2bf(v.z - bf2f(hi.z));
                hi.w = f2bf(v.w); lo.w = f2bf(v.w - bf2f(hi.w));
                *(ushort4*)&Ah[r][c4] = hi;
                *(ushort4*)&Al[r][c4] = lo;
            }
        } else {
            int r = t >> 2, c8 = (t & 3) * 8;  // 256 chunks of 8 bf16
            int gr = m0 + r;
            short8v zh = {0,0,0,0,0,0,0,0};
            short8v vh = zh, vl = zh;
            if (gr < M) {
                vh = *(const short8v*)&Ahg[(size_t)gr * K + k0 + c8];
                vl = *(const short8v*)&Alg[(size_t)gr * K + k0 + c8];
            }
            *(short8v*)&Ah[r][c8] = vh;
            *(short8v*)&Al[r][c8] = vl;
        }
        // ---- stage B tile (256 x 32) from Wt[256][K] ----
        #pragma unroll
        for (int p = 0; p < 4; ++p) {
            int idx = t + p * 256;             // 0..1023 chunks of 8 bf16
            int r = idx >> 2, c8 = (idx & 3) * 8;
            short8v vh = *(const short8v*)&Wth[(size_t)r * K + k0 + c8];
            short8v vl = *(const short8v*)&Wtl[(size_t)r * K + k0 + c8];
            *(short8v*)&Bh[r][c8] = vh;
            *(short8v*)&Bl[r][c8] = vl;
        }
        __syncthreads();

        // ---- fragments + MFMA ----
        short8v a_h[4], a_l[4], b_h[4], b_l[4];
        #pragma unroll
        for (int mf = 0; mf < 4; ++mf) {
            a_h[mf] = *(short8v*)&Ah[mf * 16 + lr][lk];
            a_l[mf] = *(short8v*)&Al[mf * 16 + lr][lk];
        }
        #pragma unroll
        for (int nf = 0; nf < 4; ++nf) {
            b_h[nf] = *(short8v*)&Bh[w * 64 + nf * 16 + lr][lk];
            b_l[nf] = *(short8v*)&Bl[w * 64 + nf * 16 + lr][lk];
        }
        #pragma unroll
        for (int mf = 0; mf < 4; ++mf)
            #pragma unroll
            for (int nf = 0; nf < 4; ++nf) {
                acc[mf][nf] = __builtin_amdgcn_mfma_f32_16x16x32_bf16(a_h[mf], b_h[nf], acc[mf][nf], 0, 0, 0);
                acc[mf][nf] = __builtin_amdgcn_mfma_f32_16x16x32_bf16(a_h[mf], b_l[nf], acc[mf][nf], 0, 0, 0);
                acc[mf][nf] = __builtin_amdgcn_mfma_f32_16x16x32_bf16(a_l[mf], b_h[nf], acc[mf][nf], 0, 0, 0);
            }
        __syncthreads();
    }

    // ---- epilogue: D row=(l>>4)*4+r, col=l&15 ----
    #pragma unroll
    for (int mf = 0; mf < 4; ++mf)
        #pragma unroll
        for (int nf = 0; nf < 4; ++nf)
            #pragma unroll
            for (int r = 0; r < 4; ++r) {
                int gr = m0 + mf * 16 + (l >> 4) * 4 + r;
                if (gr < M) C[(size_t)gr * F1 + w * 64 + nf * 16 + lr] = acc[mf][nf][r];
            }
}

// ---------------- per-node attention coefficients ----------------
__global__ void alpha_kernel(const float* __restrict__ h,
                             const float* __restrict__ a_s,
                             const float* __restrict__ a_d,
                             float* __restrict__ asrc, float* __restrict__ adst) {
    int wid  = threadIdx.x >> 6;
    int lane = threadIdx.x & 63;
    int n = blockIdx.x * 4 + wid;
    if (n >= N_NODES) return;
    const float* hn = h + (size_t)n * F1;
    float ps[HEADS], pd[HEADS];
    #pragma unroll
    for (int hh = 0; hh < HEADS; ++hh) {
        float v = hn[hh * 64 + lane];
        ps[hh] = v * a_s[hh * 64 + lane];
        pd[hh] = v * a_d[hh * 64 + lane];
    }
    #pragma unroll
    for (int o = 32; o; o >>= 1) {
        #pragma unroll
        for (int hh = 0; hh < HEADS; ++hh) {
            ps[hh] += __shfl_xor(ps[hh], o);
            pd[hh] += __shfl_xor(pd[hh], o);
        }
    }
    if (lane == 0) {
        #pragma unroll
        for (int hh = 0; hh < HEADS; ++hh) {
            asrc[n * HEADS + hh] = ps[hh];
            adst[n * HEADS + hh] = pd[hh];
        }
    }
}

// ---------------- segment softmax + aggregation (one wave per dst node) ----------------
// LAYER 1: out = split bf16 hi/lo of relu(agg + bias)   (feeds MFMA gemm2)
// LAYER 2: out = f32 head-mean + bias
template <int LAYER>
__global__ void agg_kernel(const float* __restrict__ h,
                           const float* __restrict__ asrc,
                           const float* __restrict__ adst,
                           const int* __restrict__ off,
                           const int* __restrict__ esrc,
                           const float* __restrict__ bias,
                           float* __restrict__ outF,
                           unsigned short* __restrict__ oh,
                           unsigned short* __restrict__ ol) {
    int d    = blockIdx.x;
    int lane = threadIdx.x;  // 64 threads = 1 wave
    int e0 = off[d], e1 = off[d + 1];
    float ad0 = adst[d * 4 + 0], ad1 = adst[d * 4 + 1];
    float ad2 = adst[d * 4 + 2], ad3 = adst[d * 4 + 3];
    float w0 = 0.f, w1 = 0.f, w2 = 0.f, w3 = 0.f;
    for (int i = e0 + lane; i < e1; i += 64) {
        int s = esrc[i];
        float4 as = *(const float4*)(asrc + (size_t)s * 4);
        w0 += __expf(lrelu(as.x + ad0));
        w1 += __expf(lrelu(as.y + ad1));
        w2 += __expf(lrelu(as.z + ad2));
        w3 += __expf(lrelu(as.w + ad3));
    }
    #pragma unroll
    for (int o = 32; o; o >>= 1) {
        w0 += __shfl_xor(w0, o);
        w1 += __shfl_xor(w1, o);
        w2 += __shfl_xor(w2, o);
        w3 += __shfl_xor(w3, o);
    }
    float r0 = 1.f / fmaxf(w0, 1e-16f);
    float r1 = 1.f / fmaxf(w1, 1e-16f);
    float r2 = 1.f / fmaxf(w2, 1e-16f);
    float r3 = 1.f / fmaxf(w3, 1e-16f);
    float acc0 = 0.f, acc1 = 0.f, acc2 = 0.f, acc3 = 0.f;
    for (int i = e0; i < e1; ++i) {
        int s = esrc[i];
        float4 as = *(const float4*)(asrc + (size_t)s * 4);
        float c0 = __expf(lrelu(as.x + ad0)) * r0;
        float c1 = __expf(lrelu(as.y + ad1)) * r1;
        float c2 = __expf(lrelu(as.z + ad2)) * r2;
        float c3 = __expf(lrelu(as.w + ad3)) * r3;
        const float* hs = h + (size_t)s * F1;
        acc0 += c0 * hs[lane];
        acc1 += c1 * hs[64 + lane];
        acc2 += c2 * hs[128 + lane];
        acc3 += c3 * hs[192 + lane];
    }
    if (LAYER == 1) {
        float v[4] = { fmaxf(acc0 + bias[lane], 0.f),
                       fmaxf(acc1 + bias[64 + lane], 0.f),
                       fmaxf(acc2 + bias[128 + lane], 0.f),
                       fmaxf(acc3 + bias[192 + lane], 0.f) };
        #pragma unroll
        for (int hh = 0; hh < 4; ++hh) {
            unsigned short hb = f2bf(v[hh]);
            oh[(size_t)d * F1 + hh * 64 + lane] = hb;
            ol[(size_t)d * F1 + hh * 64 + lane] = f2bf(v[hh] - bf2f(hb));
        }
    } else {
        outF[(size_t)d * HID + lane] = 0.25f * (acc0 + acc1 + acc2 + acc3) + bias[lane];
    }
}

// ---------------- global mean pool: one block per graph, batch is sorted ----------------
__device__ __forceinline__ int lowerb(const int* __restrict__ a, int n, int v) {
    int lo = 0, hi = n;
    while (lo < hi) { int m = (lo + hi) >> 1; if (a[m] < v) lo = m + 1; else hi = m; }
    return lo;
}

__global__ void pool2_kernel(const float* __restrict__ h2,
                             const int* __restrict__ batch,
                             float* __restrict__ pooled) {
    __shared__ float sh[4][HID];
    int b = blockIdx.x;
    int t = threadIdx.x, w = t >> 6, c = t & 63;
    int lo = lowerb(batch, N_NODES, b);
    int hi = lowerb(batch, N_NODES, b + 1);
    float s = 0.f;
    for (int n = lo + w; n < hi; n += 4) s += h2[(size_t)n * HID + c];
    sh[w][c] = s;
    __syncthreads();
    if (w == 0) {
        float tot = sh[0][c] + sh[1][c] + sh[2][c] + sh[3][c];
        pooled[b * HID + c] = tot / fmaxf((float)(hi - lo), 1.f);
    }
}

// ---------------- graph MLP ----------------
__global__ void mlp_kernel(const float* __restrict__ pooled,
                           const float* __restrict__ Wm1, const float* __restrict__ bm1,
                           const float* __restrict__ Wm2, const float* __restrict__ bm2,
                           float* __restrict__ out) {
    __shared__ float P[NB][HID];
    __shared__ float Hh[NB][HID];
    int t = threadIdx.x;
    for (int i = t; i < NB * HID; i += 256) P[i / HID][i % HID] = pooled[i];
    __syncthreads();
    for (int i = t; i < NB * HID; i += 256) {
        int b = i / HID, c = i % HID;
        float s = bm1[c];
        for (int k = 0; k < HID; ++k) s += P[b][k] * Wm1[k * HID + c];
        Hh[b][c] = fmaxf(s, 0.f);
    }
    __syncthreads();
    if (t < NB) {
        float s = bm2[0];
        for (int k = 0; k < HID; ++k) s += Hh[t][k] * Wm2[k];
        out[t] = s;
    }
}

extern "C" void kernel_launch(void* const* d_in, const int* in_sizes, int n_in,
                              void* d_out, int out_size, void* d_ws, size_t ws_size,
                              hipStream_t stream) {
    const float* x   = (const float*)d_in[0];
    const int*   ei  = (const int*)d_in[1];
    const int*   bat = (const int*)d_in[2];
    const float* W1  = (const float*)d_in[3];
    const float* as1 = (const float*)d_in[4];
    const float* ad1 = (const float*)d_in[5];
    const float* b1  = (const float*)d_in[6];
    const float* W2  = (const float*)d_in[7];
    const float* as2 = (const float*)d_in[8];
    const float* ad2 = (const float*)d_in[9];
    const float* b2  = (const float*)d_in[10];
    const float* Wm1 = (const float*)d_in[11];
    const float* bm1 = (const float*)d_in[12];
    const float* Wm2 = (const float*)d_in[13];
    const float* bm2 = (const float*)d_in[14];
    float* out = (float*)d_out;

    char* ws = (char*)d_ws;
    size_t cursor = 0;
    auto alloc = [&](size_t bytes) {
        void* p = ws + cursor;
        cursor += (bytes + 511) & ~(size_t)511;
        return p;
    };
    int*   deg    = (int*)alloc((size_t)N_NODES * 4);
    int*   off    = (int*)alloc((size_t)(N_NODES + 1) * 4);
    int*   esrc   = (int*)alloc((size_t)ETOT * 4);
    float* bufH   = (float*)alloc((size_t)N_NODES * F1 * 4);              // gemm out f32
    // union region (51.2 MB): oh/ol after agg1; bufO (agg2 out) aliases oh after gemm2
    char*  U      = (char*)alloc((size_t)N_NODES * F1 * 4);
    unsigned short* oh   = (unsigned short*)U;                            // [N,256] bf16 hi
    unsigned short* olsp = (unsigned short*)(U + (size_t)N_NODES * F1 * 2);
    float* bufO   = (float*)U;                                            // [N,64] f32 (after gemm2)
    float* asrc   = (float*)alloc((size_t)N_NODES * HEADS * 4);
    float* adst   = (float*)alloc((size_t)N_NODES * HEADS * 4);
    float* pooled = (float*)alloc((size_t)NB * HID * 4);
    unsigned short* W1th = (unsigned short*)alloc((size_t)256 * IN_C * 2);
    unsigned short* W1tl = (unsigned short*)alloc((size_t)256 * IN_C * 2);
    unsigned short* W2th = (unsigned short*)alloc((size_t)256 * F1 * 2);
    unsigned short* W2tl = (unsigned short*)alloc((size_t)256 * F1 * 2);

    hipMemsetAsync(deg, 0, (size_t)N_NODES * 4, stream);

    deg_kernel<<<(ETOT + 255) / 256, 256, 0, stream>>>(ei, deg);
    scan_kernel<<<1, 1024, 0, stream>>>(deg, off);
    scatter_kernel<<<(ETOT + 255) / 256, 256, 0, stream>>>(ei, off, deg, esrc);

    convw_kernel<<<(IN_C * 256 + 255) / 256, 256, 0, stream>>>(W1, W1th, W1tl, IN_C);
    convw_kernel<<<(F1 * 256 + 255) / 256, 256, 0, stream>>>(W2, W2th, W2tl, F1);

    const int GB = (N_NODES + 63) / 64;
    // layer 1
    gemm_mfma<true><<<GB, 256, 0, stream>>>(x, nullptr, nullptr, W1th, W1tl, bufH, N_NODES, IN_C);
    alpha_kernel<<<(N_NODES + 3) / 4, 256, 0, stream>>>(bufH, as1, ad1, asrc, adst);
    agg_kernel<1><<<N_NODES, 64, 0, stream>>>(bufH, asrc, adst, off, esrc, b1, nullptr, oh, olsp);

    // layer 2
    gemm_mfma<false><<<GB, 256, 0, stream>>>(nullptr, oh, olsp, W2th, W2tl, bufH, N_NODES, F1);
    alpha_kernel<<<(N_NODES + 3) / 4, 256, 0, stream>>>(bufH, as2, ad2, asrc, adst);
    agg_kernel<2><<<N_NODES, 64, 0, stream>>>(bufH, asrc, adst, off, esrc, b2, bufO, nullptr, nullptr);

    // pool + MLP
    pool2_kernel<<<NB, 256, 0, stream>>>(bufO, bat, pooled);
    mlp_kernel<<<1, 256, 0, stream>>>(pooled, Wm1, bm1, Wm2, bm2, out);
}

// Round 4
// 465.576 us; speedup vs baseline: 2.3750x; 1.3541x over previous
//
#include <hip/hip_runtime.h>
#include <hip/hip_bf16.h>

#define N_NODES 50000
#define N_EDGES 800000
#define ETOT    (N_EDGES + N_NODES)
#define NB      64
#define IN_C    128
#define HID     64
#define HEADS   4
#define F1      (HEADS * HID)   /* 256 */
#define NEG     0.2f

typedef __attribute__((ext_vector_type(8))) short  short8v;
typedef __attribute__((ext_vector_type(4))) float  float4v;

__device__ __forceinline__ float lrelu(float x) { return x >= 0.f ? x : NEG * x; }

// round-to-nearest-even f32 -> bf16 bits
__device__ __forceinline__ unsigned short f2bf(float f) {
    unsigned u = __float_as_uint(f);
    u += 0x7FFFu + ((u >> 16) & 1u);
    return (unsigned short)(u >> 16);
}
__device__ __forceinline__ float bf2f(unsigned short h) {
    return __uint_as_float(((unsigned)h) << 16);
}

// ---------------- CSR build ----------------
__global__ void deg_kernel(const int* __restrict__ ei, int* __restrict__ deg) {
    int e = blockIdx.x * 256 + threadIdx.x;
    if (e >= ETOT) return;
    int d = (e < N_EDGES) ? ei[N_EDGES + e] : (e - N_EDGES);
    atomicAdd(&deg[d], 1);
}

__global__ void scan_kernel(int* __restrict__ deg, int* __restrict__ off) {
    __shared__ int sh[1024];
    int t = threadIdx.x;
    const int CH = (N_NODES + 1023) / 1024;
    int start = t * CH;
    int end   = min(start + CH, N_NODES);
    int s = 0;
    for (int i = start; i < end; ++i) s += deg[i];
    sh[t] = s;
    __syncthreads();
    for (int o = 1; o < 1024; o <<= 1) {
        int v = (t >= o) ? sh[t - o] : 0;
        __syncthreads();
        sh[t] += v;
        __syncthreads();
    }
    int base = (t == 0) ? 0 : sh[t - 1];
    for (int i = start; i < end; ++i) { off[i] = base; base += deg[i]; }
    if (t == 1023) off[N_NODES] = sh[1023];
    __syncthreads();
    for (int i = start; i < end; ++i) deg[i] = 0;  // reuse as cursor
}

__global__ void scatter_kernel(const int* __restrict__ ei, const int* __restrict__ off,
                               int* __restrict__ cursor, int* __restrict__ esrc) {
    int e = blockIdx.x * 256 + threadIdx.x;
    if (e >= ETOT) return;
    int s, d;
    if (e < N_EDGES) { s = ei[e]; d = ei[N_EDGES + e]; }
    else             { s = d = e - N_EDGES; }
    int pos = off[d] + atomicAdd(&cursor[d], 1);
    esrc[pos] = s;
}

// ---------------- W [K][256] f32 -> transposed split bf16 Wt[256][K] hi/lo ----------------
__global__ void convw_kernel(const float* __restrict__ W,
                             unsigned short* __restrict__ Wth,
                             unsigned short* __restrict__ Wtl, int K) {
    int i = blockIdx.x * 256 + threadIdx.x;
    if (i >= K * 256) return;
    int k = i >> 8, n = i & 255;
    float v = W[i];
    unsigned short h = f2bf(v);
    Wth[n * K + k] = h;
    Wtl[n * K + k] = f2bf(v - bf2f(h));
}

// ---------------- split-bf16 MFMA GEMM + fused alpha + bf16 output ----------------
// C[M,256] = A[M,K] @ W[K,256]; writes Cb (bf16) and per-node alpha_src/alpha_dst.
// Wave w owns head w's 64 columns. 3-product split: Ah*Bh + Ah*Bl + Al*Bh.
template <bool SPLIT_A>
__global__ __launch_bounds__(256) void gemm_mfma(const float* __restrict__ Af32,
                                                 const unsigned short* __restrict__ Ahg,
                                                 const unsigned short* __restrict__ Alg,
                                                 const unsigned short* __restrict__ Wth,
                                                 const unsigned short* __restrict__ Wtl,
                                                 const float* __restrict__ a_s,
                                                 const float* __restrict__ a_d,
                                                 unsigned short* __restrict__ Cb,
                                                 float* __restrict__ asrcO,
                                                 float* __restrict__ adstO,
                                                 int M, int K) {
    __shared__ unsigned short Ah[64][40], Al[64][40];    // 32 + 8 pad
    __shared__ unsigned short Bh[256][40], Bl[256][40];
    int t  = threadIdx.x;
    int m0 = blockIdx.x * 64;
    int w  = t >> 6, l = t & 63;
    int lr = l & 15, lk = (l >> 4) * 8;

    float asv[4], adv[4];
    #pragma unroll
    for (int nf = 0; nf < 4; ++nf) {
        asv[nf] = a_s[w * 64 + nf * 16 + lr];
        adv[nf] = a_d[w * 64 + nf * 16 + lr];
    }

    float4v acc[4][4];
    #pragma unroll
    for (int mf = 0; mf < 4; ++mf)
        #pragma unroll
        for (int nf = 0; nf < 4; ++nf)
            acc[mf][nf] = (float4v){0.f, 0.f, 0.f, 0.f};

    for (int k0 = 0; k0 < K; k0 += 32) {
        if (SPLIT_A) {
            #pragma unroll
            for (int p = 0; p < 2; ++p) {
                int idx = t + p * 256;
                int r = idx >> 3, c4 = (idx & 7) * 4;
                int gr = m0 + r;
                float4 v = make_float4(0.f, 0.f, 0.f, 0.f);
                if (gr < M) v = *(const float4*)&Af32[(size_t)gr * K + k0 + c4];
                ushort4 hi, lo;
                hi.x = f2bf(v.x); lo.x = f2bf(v.x - bf2f(hi.x));
                hi.y = f2bf(v.y); lo.y = f2bf(v.y - bf2f(hi.y));
                hi.z = f2bf(v.z); lo.z = f2bf(v.z - bf2f(hi.z));
                hi.w = f2bf(v.w); lo.w = f2bf(v.w - bf2f(hi.w));
                *(ushort4*)&Ah[r][c4] = hi;
                *(ushort4*)&Al[r][c4] = lo;
            }
        } else {
            int r = t >> 2, c8 = (t & 3) * 8;
            int gr = m0 + r;
            short8v zh = {0,0,0,0,0,0,0,0};
            short8v vh = zh, vl = zh;
            if (gr < M) {
                vh = *(const short8v*)&Ahg[(size_t)gr * K + k0 + c8];
                vl = *(const short8v*)&Alg[(size_t)gr * K + k0 + c8];
            }
            *(short8v*)&Ah[r][c8] = vh;
            *(short8v*)&Al[r][c8] = vl;
        }
        #pragma unroll
        for (int p = 0; p < 4; ++p) {
            int idx = t + p * 256;
            int r = idx >> 2, c8 = (idx & 3) * 8;
            short8v vh = *(const short8v*)&Wth[(size_t)r * K + k0 + c8];
            short8v vl = *(const short8v*)&Wtl[(size_t)r * K + k0 + c8];
            *(short8v*)&Bh[r][c8] = vh;
            *(short8v*)&Bl[r][c8] = vl;
        }
        __syncthreads();

        short8v a_hf[4], a_lf[4], b_hf[4], b_lf[4];
        #pragma unroll
        for (int mf = 0; mf < 4; ++mf) {
            a_hf[mf] = *(short8v*)&Ah[mf * 16 + lr][lk];
            a_lf[mf] = *(short8v*)&Al[mf * 16 + lr][lk];
        }
        #pragma unroll
        for (int nf = 0; nf < 4; ++nf) {
            b_hf[nf] = *(short8v*)&Bh[w * 64 + nf * 16 + lr][lk];
            b_lf[nf] = *(short8v*)&Bl[w * 64 + nf * 16 + lr][lk];
        }
        #pragma unroll
        for (int mf = 0; mf < 4; ++mf)
            #pragma unroll
            for (int nf = 0; nf < 4; ++nf) {
                acc[mf][nf] = __builtin_amdgcn_mfma_f32_16x16x32_bf16(a_hf[mf], b_hf[nf], acc[mf][nf], 0, 0, 0);
                acc[mf][nf] = __builtin_amdgcn_mfma_f32_16x16x32_bf16(a_hf[mf], b_lf[nf], acc[mf][nf], 0, 0, 0);
                acc[mf][nf] = __builtin_amdgcn_mfma_f32_16x16x32_bf16(a_lf[mf], b_hf[nf], acc[mf][nf], 0, 0, 0);
            }
        __syncthreads();
    }

    // ---- fused alpha: per-row dot with a_s/a_d (head w), 16-lane reduce ----
    #pragma unroll
    for (int mf = 0; mf < 4; ++mf)
        #pragma unroll
        for (int r = 0; r < 4; ++r) {
            float ps = acc[mf][0][r] * asv[0] + acc[mf][1][r] * asv[1]
                     + acc[mf][2][r] * asv[2] + acc[mf][3][r] * asv[3];
            float pd = acc[mf][0][r] * adv[0] + acc[mf][1][r] * adv[1]
                     + acc[mf][2][r] * adv[2] + acc[mf][3][r] * adv[3];
            #pragma unroll
            for (int o = 8; o; o >>= 1) {
                ps += __shfl_xor(ps, o);
                pd += __shfl_xor(pd, o);
            }
            int gr = m0 + mf * 16 + (l >> 4) * 4 + r;
            if (lr == 0 && gr < M) {
                asrcO[gr * 4 + w] = ps;
                adstO[gr * 4 + w] = pd;
            }
        }

    // ---- bf16 C write (gather source for agg) ----
    #pragma unroll
    for (int mf = 0; mf < 4; ++mf)
        #pragma unroll
        for (int nf = 0; nf < 4; ++nf)
            #pragma unroll
            for (int r = 0; r < 4; ++r) {
                int gr = m0 + mf * 16 + (l >> 4) * 4 + r;
                if (gr < M) Cb[(size_t)gr * F1 + w * 64 + nf * 16 + lr] = f2bf(acc[mf][nf][r]);
            }
}

// ---------------- fused segment softmax + aggregation (one wave per dst node) ----------------
// Single pass: acc = sum(c*h_bf16[src]), den = sum(c); out = acc/den.
// Per-64-edge chunk: lane e computes coeffs for edge e -> LDS; then serial broadcast loop.
// LAYER 1: out = split bf16 hi/lo of relu(agg + bias); LAYER 2: f32 head-mean + bias.
template <int LAYER>
__global__ void agg_kernel(const unsigned short* __restrict__ hb,
                           const float* __restrict__ asrc,
                           const float* __restrict__ adst,
                           const int* __restrict__ off,
                           const int* __restrict__ esrc,
                           const float* __restrict__ bias,
                           float* __restrict__ outF,
                           unsigned short* __restrict__ oh,
                           unsigned short* __restrict__ ol) {
    __shared__ int   ssh[64];
    __shared__ float cf[64][4];
    int d    = blockIdx.x;
    int lane = threadIdx.x;  // 64 = 1 wave
    int e0 = off[d], e1 = off[d + 1];
    float4 ad = *(const float4*)(adst + (size_t)d * 4);
    float den0 = 0.f, den1 = 0.f, den2 = 0.f, den3 = 0.f;
    float acc0 = 0.f, acc1 = 0.f, acc2 = 0.f, acc3 = 0.f;

    for (int base = e0; base < e1; base += 64) {
        int cnt = min(64, e1 - base);
        if (lane < cnt) {
            int s = esrc[base + lane];
            ssh[lane] = s;
            float4 as = *(const float4*)(asrc + (size_t)s * 4);
            cf[lane][0] = __expf(lrelu(as.x + ad.x));
            cf[lane][1] = __expf(lrelu(as.y + ad.y));
            cf[lane][2] = __expf(lrelu(as.z + ad.z));
            cf[lane][3] = __expf(lrelu(as.w + ad.w));
        }
        __syncthreads();
        #pragma unroll 2
        for (int i = 0; i < cnt; ++i) {
            int s = ssh[i];
            float4 c = *(const float4*)cf[i];
            den0 += c.x; den1 += c.y; den2 += c.z; den3 += c.w;
            const unsigned short* hs = hb + (size_t)s * F1;
            acc0 += c.x * bf2f(hs[lane]);
            acc1 += c.y * bf2f(hs[64 + lane]);
            acc2 += c.z * bf2f(hs[128 + lane]);
            acc3 += c.w * bf2f(hs[192 + lane]);
        }
        __syncthreads();
    }

    float r0 = 1.f / fmaxf(den0, 1e-16f);
    float r1 = 1.f / fmaxf(den1, 1e-16f);
    float r2 = 1.f / fmaxf(den2, 1e-16f);
    float r3 = 1.f / fmaxf(den3, 1e-16f);
    if (LAYER == 1) {
        float v[4] = { fmaxf(acc0 * r0 + bias[lane], 0.f),
                       fmaxf(acc1 * r1 + bias[64 + lane], 0.f),
                       fmaxf(acc2 * r2 + bias[128 + lane], 0.f),
                       fmaxf(acc3 * r3 + bias[192 + lane], 0.f) };
        #pragma unroll
        for (int hh = 0; hh < 4; ++hh) {
            unsigned short hbv = f2bf(v[hh]);
            oh[(size_t)d * F1 + hh * 64 + lane] = hbv;
            ol[(size_t)d * F1 + hh * 64 + lane] = f2bf(v[hh] - bf2f(hbv));
        }
    } else {
        outF[(size_t)d * HID + lane] =
            0.25f * (acc0 * r0 + acc1 * r1 + acc2 * r2 + acc3 * r3) + bias[lane];
    }
}

// ---------------- global mean pool: one block per graph, batch is sorted ----------------
__device__ __forceinline__ int lowerb(const int* __restrict__ a, int n, int v) {
    int lo = 0, hi = n;
    while (lo < hi) { int m = (lo + hi) >> 1; if (a[m] < v) lo = m + 1; else hi = m; }
    return lo;
}

__global__ void pool2_kernel(const float* __restrict__ h2,
                             const int* __restrict__ batch,
                             float* __restrict__ pooled) {
    __shared__ float sh[4][HID];
    int b = blockIdx.x;
    int t = threadIdx.x, w = t >> 6, c = t & 63;
    int lo = lowerb(batch, N_NODES, b);
    int hi = lowerb(batch, N_NODES, b + 1);
    float s = 0.f;
    for (int n = lo + w; n < hi; n += 4) s += h2[(size_t)n * HID + c];
    sh[w][c] = s;
    __syncthreads();
    if (w == 0) {
        float tot = sh[0][c] + sh[1][c] + sh[2][c] + sh[3][c];
        pooled[b * HID + c] = tot / fmaxf((float)(hi - lo), 1.f);
    }
}

// ---------------- graph MLP ----------------
__global__ void mlp_kernel(const float* __restrict__ pooled,
                           const float* __restrict__ Wm1, const float* __restrict__ bm1,
                           const float* __restrict__ Wm2, const float* __restrict__ bm2,
                           float* __restrict__ out) {
    __shared__ float P[NB][HID];
    __shared__ float Hh[NB][HID];
    int t = threadIdx.x;
    for (int i = t; i < NB * HID; i += 256) P[i / HID][i % HID] = pooled[i];
    __syncthreads();
    for (int i = t; i < NB * HID; i += 256) {
        int b = i / HID, c = i % HID;
        float s = bm1[c];
        for (int k = 0; k < HID; ++k) s += P[b][k] * Wm1[k * HID + c];
        Hh[b][c] = fmaxf(s, 0.f);
    }
    __syncthreads();
    if (t < NB) {
        float s = bm2[0];
        for (int k = 0; k < HID; ++k) s += Hh[t][k] * Wm2[k];
        out[t] = s;
    }
}

extern "C" void kernel_launch(void* const* d_in, const int* in_sizes, int n_in,
                              void* d_out, int out_size, void* d_ws, size_t ws_size,
                              hipStream_t stream) {
    const float* x   = (const float*)d_in[0];
    const int*   ei  = (const int*)d_in[1];
    const int*   bat = (const int*)d_in[2];
    const float* W1  = (const float*)d_in[3];
    const float* as1 = (const float*)d_in[4];
    const float* ad1 = (const float*)d_in[5];
    const float* b1  = (const float*)d_in[6];
    const float* W2  = (const float*)d_in[7];
    const float* as2 = (const float*)d_in[8];
    const float* ad2 = (const float*)d_in[9];
    const float* b2  = (const float*)d_in[10];
    const float* Wm1 = (const float*)d_in[11];
    const float* bm1 = (const float*)d_in[12];
    const float* Wm2 = (const float*)d_in[13];
    const float* bm2 = (const float*)d_in[14];
    float* out = (float*)d_out;

    char* ws = (char*)d_ws;
    size_t cursor = 0;
    auto alloc = [&](size_t bytes) {
        void* p = ws + cursor;
        cursor += (bytes + 511) & ~(size_t)511;
        return p;
    };
    int*   deg    = (int*)alloc((size_t)N_NODES * 4);
    int*   off    = (int*)alloc((size_t)(N_NODES + 1) * 4);
    int*   esrc   = (int*)alloc((size_t)ETOT * 4);
    unsigned short* bufHb = (unsigned short*)alloc((size_t)N_NODES * F1 * 2);  // gemm bf16 out
    // union region (51.2 MB): oh/ol after agg1; bufO (agg2 out) aliases oh after gemm2
    char*  U      = (char*)alloc((size_t)N_NODES * F1 * 4);
    unsigned short* oh   = (unsigned short*)U;
    unsigned short* olsp = (unsigned short*)(U + (size_t)N_NODES * F1 * 2);
    float* bufO   = (float*)U;
    float* asrc   = (float*)alloc((size_t)N_NODES * HEADS * 4);
    float* adst   = (float*)alloc((size_t)N_NODES * HEADS * 4);
    float* pooled = (float*)alloc((size_t)NB * HID * 4);
    unsigned short* W1th = (unsigned short*)alloc((size_t)256 * IN_C * 2);
    unsigned short* W1tl = (unsigned short*)alloc((size_t)256 * IN_C * 2);
    unsigned short* W2th = (unsigned short*)alloc((size_t)256 * F1 * 2);
    unsigned short* W2tl = (unsigned short*)alloc((size_t)256 * F1 * 2);

    hipMemsetAsync(deg, 0, (size_t)N_NODES * 4, stream);

    deg_kernel<<<(ETOT + 255) / 256, 256, 0, stream>>>(ei, deg);
    scan_kernel<<<1, 1024, 0, stream>>>(deg, off);
    scatter_kernel<<<(ETOT + 255) / 256, 256, 0, stream>>>(ei, off, deg, esrc);

    convw_kernel<<<(IN_C * 256 + 255) / 256, 256, 0, stream>>>(W1, W1th, W1tl, IN_C);
    convw_kernel<<<(F1 * 256 + 255) / 256, 256, 0, stream>>>(W2, W2th, W2tl, F1);

    const int GB = (N_NODES + 63) / 64;
    // layer 1 (gemm writes bf16 h + alpha_src/dst; agg gathers bf16, emits split bf16)
    gemm_mfma<true><<<GB, 256, 0, stream>>>(x, nullptr, nullptr, W1th, W1tl,
                                            as1, ad1, bufHb, asrc, adst, N_NODES, IN_C);
    agg_kernel<1><<<N_NODES, 64, 0, stream>>>(bufHb, asrc, adst, off, esrc, b1,
                                              nullptr, oh, olsp);

    // layer 2
    gemm_mfma<false><<<GB, 256, 0, stream>>>(nullptr, oh, olsp, W2th, W2tl,
                                             as2, ad2, bufHb, asrc, adst, N_NODES, F1);
    agg_kernel<2><<<N_NODES, 64, 0, stream>>>(bufHb, asrc, adst, off, esrc, b2,
                                              bufO, nullptr, nullptr);

    // pool + MLP
    pool2_kernel<<<NB, 256, 0, stream>>>(bufO, bat, pooled);
    mlp_kernel<<<1, 256, 0, stream>>>(pooled, Wm1, bm1, Wm2, bm2, out);
}

// Round 5
// 381.890 us; speedup vs baseline: 2.8955x; 1.2191x over previous
//
#include <hip/hip_runtime.h>
#include <hip/hip_bf16.h>

#define N_NODES 50000
#define N_EDGES 800000
#define ETOT    (N_EDGES + N_NODES)
#define NB      64
#define IN_C    128
#define HID     64
#define HEADS   4
#define F1      (HEADS * HID)   /* 256 */
#define NEG     0.2f
#define SCAN_NBLK ((N_NODES + 255) / 256)   /* 196 */

typedef __attribute__((ext_vector_type(8))) short  short8v;
typedef __attribute__((ext_vector_type(4))) float  float4v;

__device__ __forceinline__ float lrelu(float x) { return x >= 0.f ? x : NEG * x; }

// round-to-nearest-even f32 -> bf16 bits
__device__ __forceinline__ unsigned short f2bf(float f) {
    unsigned u = __float_as_uint(f);
    u += 0x7FFFu + ((u >> 16) & 1u);
    return (unsigned short)(u >> 16);
}
__device__ __forceinline__ float bf2f(unsigned short h) {
    return __uint_as_float(((unsigned)h) << 16);
}

// ---------------- CSR build ----------------
__global__ void deg_kernel(const int* __restrict__ ei, int* __restrict__ deg) {
    int e = blockIdx.x * 256 + threadIdx.x;
    if (e >= ETOT) return;
    int d = (e < N_EDGES) ? ei[N_EDGES + e] : (e - N_EDGES);
    atomicAdd(&deg[d], 1);
}

// 3-phase grid-wide exclusive scan of deg[N_NODES] -> off[N_NODES+1]
__global__ void scan1_kernel(const int* __restrict__ deg, int* __restrict__ part) {
    __shared__ int sh[256];
    int t = threadIdx.x;
    int i = blockIdx.x * 256 + t;
    sh[t] = (i < N_NODES) ? deg[i] : 0;
    __syncthreads();
    #pragma unroll
    for (int o = 128; o; o >>= 1) {
        if (t < o) sh[t] += sh[t + o];
        __syncthreads();
    }
    if (t == 0) part[blockIdx.x] = sh[0];
}

__global__ void scan2_kernel(int* __restrict__ part, int* __restrict__ off) {
    __shared__ int sh[256];
    int t = threadIdx.x;
    int v = (t < SCAN_NBLK) ? part[t] : 0;
    sh[t] = v;
    __syncthreads();
    #pragma unroll
    for (int o = 1; o < 256; o <<= 1) {
        int u = (t >= o) ? sh[t - o] : 0;
        __syncthreads();
        sh[t] += u;
        __syncthreads();
    }
    if (t < SCAN_NBLK) part[t] = sh[t] - v;       // exclusive block base
    if (t == 255) off[N_NODES] = sh[255];
}

__global__ void scan3_kernel(int* __restrict__ deg, const int* __restrict__ part,
                             int* __restrict__ off) {
    __shared__ int sh[256];
    int t = threadIdx.x;
    int i = blockIdx.x * 256 + t;
    int v = (i < N_NODES) ? deg[i] : 0;
    sh[t] = v;
    __syncthreads();
    #pragma unroll
    for (int o = 1; o < 256; o <<= 1) {
        int u = (t >= o) ? sh[t - o] : 0;
        __syncthreads();
        sh[t] += u;
        __syncthreads();
    }
    if (i < N_NODES) {
        off[i] = part[blockIdx.x] + sh[t] - v;
        deg[i] = 0;                                // reuse as cursor
    }
}

__global__ void scatter_kernel(const int* __restrict__ ei, const int* __restrict__ off,
                               int* __restrict__ cursor, int* __restrict__ esrc) {
    int e = blockIdx.x * 256 + threadIdx.x;
    if (e >= ETOT) return;
    int s, d;
    if (e < N_EDGES) { s = ei[e]; d = ei[N_EDGES + e]; }
    else             { s = d = e - N_EDGES; }
    int pos = off[d] + atomicAdd(&cursor[d], 1);
    esrc[pos] = s;
}

// ---------------- W [K][256] f32 -> transposed split bf16 Wt[256][K] hi/lo ----------------
__global__ void convw_kernel(const float* __restrict__ W,
                             unsigned short* __restrict__ Wth,
                             unsigned short* __restrict__ Wtl, int K) {
    int i = blockIdx.x * 256 + threadIdx.x;
    if (i >= K * 256) return;
    int k = i >> 8, n = i & 255;
    float v = W[i];
    unsigned short h = f2bf(v);
    Wth[n * K + k] = h;
    Wtl[n * K + k] = f2bf(v - bf2f(h));
}

// ---------------- split-bf16 MFMA GEMM + fused alpha + bf16 output ----------------
// C[M,256] = A[M,K] @ W[K,256]; writes Cb (bf16) and per-node alpha_src/alpha_dst.
// Wave w owns head w's 64 columns. 3-product split: Ah*Bh + Ah*Bl + Al*Bh.
template <bool SPLIT_A>
__global__ __launch_bounds__(256) void gemm_mfma(const float* __restrict__ Af32,
                                                 const unsigned short* __restrict__ Ahg,
                                                 const unsigned short* __restrict__ Alg,
                                                 const unsigned short* __restrict__ Wth,
                                                 const unsigned short* __restrict__ Wtl,
                                                 const float* __restrict__ a_s,
                                                 const float* __restrict__ a_d,
                                                 unsigned short* __restrict__ Cb,
                                                 float* __restrict__ asrcO,
                                                 float* __restrict__ adstO,
                                                 int M, int K) {
    __shared__ unsigned short Ah[64][40], Al[64][40];    // 32 + 8 pad
    __shared__ unsigned short Bh[256][40], Bl[256][40];
    int t  = threadIdx.x;
    int m0 = blockIdx.x * 64;
    int w  = t >> 6, l = t & 63;
    int lr = l & 15, lk = (l >> 4) * 8;

    float asv[4], adv[4];
    #pragma unroll
    for (int nf = 0; nf < 4; ++nf) {
        asv[nf] = a_s[w * 64 + nf * 16 + lr];
        adv[nf] = a_d[w * 64 + nf * 16 + lr];
    }

    float4v acc[4][4];
    #pragma unroll
    for (int mf = 0; mf < 4; ++mf)
        #pragma unroll
        for (int nf = 0; nf < 4; ++nf)
            acc[mf][nf] = (float4v){0.f, 0.f, 0.f, 0.f};

    for (int k0 = 0; k0 < K; k0 += 32) {
        if (SPLIT_A) {
            #pragma unroll
            for (int p = 0; p < 2; ++p) {
                int idx = t + p * 256;
                int r = idx >> 3, c4 = (idx & 7) * 4;
                int gr = m0 + r;
                float4 v = make_float4(0.f, 0.f, 0.f, 0.f);
                if (gr < M) v = *(const float4*)&Af32[(size_t)gr * K + k0 + c4];
                ushort4 hi, lo;
                hi.x = f2bf(v.x); lo.x = f2bf(v.x - bf2f(hi.x));
                hi.y = f2bf(v.y); lo.y = f2bf(v.y - bf2f(hi.y));
                hi.z = f2bf(v.z); lo.z = f2bf(v.z - bf2f(hi.z));
                hi.w = f2bf(v.w); lo.w = f2bf(v.w - bf2f(hi.w));
                *(ushort4*)&Ah[r][c4] = hi;
                *(ushort4*)&Al[r][c4] = lo;
            }
        } else {
            int r = t >> 2, c8 = (t & 3) * 8;
            int gr = m0 + r;
            short8v zh = {0,0,0,0,0,0,0,0};
            short8v vh = zh, vl = zh;
            if (gr < M) {
                vh = *(const short8v*)&Ahg[(size_t)gr * K + k0 + c8];
                vl = *(const short8v*)&Alg[(size_t)gr * K + k0 + c8];
            }
            *(short8v*)&Ah[r][c8] = vh;
            *(short8v*)&Al[r][c8] = vl;
        }
        #pragma unroll
        for (int p = 0; p < 4; ++p) {
            int idx = t + p * 256;
            int r = idx >> 2, c8 = (idx & 3) * 8;
            short8v vh = *(const short8v*)&Wth[(size_t)r * K + k0 + c8];
            short8v vl = *(const short8v*)&Wtl[(size_t)r * K + k0 + c8];
            *(short8v*)&Bh[r][c8] = vh;
            *(short8v*)&Bl[r][c8] = vl;
        }
        __syncthreads();

        short8v a_hf[4], a_lf[4], b_hf[4], b_lf[4];
        #pragma unroll
        for (int mf = 0; mf < 4; ++mf) {
            a_hf[mf] = *(short8v*)&Ah[mf * 16 + lr][lk];
            a_lf[mf] = *(short8v*)&Al[mf * 16 + lr][lk];
        }
        #pragma unroll
        for (int nf = 0; nf < 4; ++nf) {
            b_hf[nf] = *(short8v*)&Bh[w * 64 + nf * 16 + lr][lk];
            b_lf[nf] = *(short8v*)&Bl[w * 64 + nf * 16 + lr][lk];
        }
        #pragma unroll
        for (int mf = 0; mf < 4; ++mf)
            #pragma unroll
            for (int nf = 0; nf < 4; ++nf) {
                acc[mf][nf] = __builtin_amdgcn_mfma_f32_16x16x32_bf16(a_hf[mf], b_hf[nf], acc[mf][nf], 0, 0, 0);
                acc[mf][nf] = __builtin_amdgcn_mfma_f32_16x16x32_bf16(a_hf[mf], b_lf[nf], acc[mf][nf], 0, 0, 0);
                acc[mf][nf] = __builtin_amdgcn_mfma_f32_16x16x32_bf16(a_lf[mf], b_hf[nf], acc[mf][nf], 0, 0, 0);
            }
        __syncthreads();
    }

    // ---- fused alpha: per-row dot with a_s/a_d (head w), 16-lane reduce ----
    #pragma unroll
    for (int mf = 0; mf < 4; ++mf)
        #pragma unroll
        for (int r = 0; r < 4; ++r) {
            float ps = acc[mf][0][r] * asv[0] + acc[mf][1][r] * asv[1]
                     + acc[mf][2][r] * asv[2] + acc[mf][3][r] * asv[3];
            float pd = acc[mf][0][r] * adv[0] + acc[mf][1][r] * adv[1]
                     + acc[mf][2][r] * adv[2] + acc[mf][3][r] * adv[3];
            #pragma unroll
            for (int o = 8; o; o >>= 1) {
                ps += __shfl_xor(ps, o);
                pd += __shfl_xor(pd, o);
            }
            int gr = m0 + mf * 16 + (l >> 4) * 4 + r;
            if (lr == 0 && gr < M) {
                asrcO[gr * 4 + w] = ps;
                adstO[gr * 4 + w] = pd;
            }
        }

    // ---- bf16 C write (gather source for agg) ----
    #pragma unroll
    for (int mf = 0; mf < 4; ++mf)
        #pragma unroll
        for (int nf = 0; nf < 4; ++nf)
            #pragma unroll
            for (int r = 0; r < 4; ++r) {
                int gr = m0 + mf * 16 + (l >> 4) * 4 + r;
                if (gr < M) Cb[(size_t)gr * F1 + w * 64 + nf * 16 + lr] = f2bf(acc[mf][nf][r]);
            }
}

// ---------------- fused segment softmax + aggregation (one wave per dst node) ----------------
template <int LAYER>
__global__ void agg_kernel(const unsigned short* __restrict__ hb,
                           const float* __restrict__ asrc,
                           const float* __restrict__ adst,
                           const int* __restrict__ off,
                           const int* __restrict__ esrc,
                           const float* __restrict__ bias,
                           float* __restrict__ outF,
                           unsigned short* __restrict__ oh,
                           unsigned short* __restrict__ ol) {
    __shared__ int   ssh[64];
    __shared__ float cf[64][4];
    int d    = blockIdx.x;
    int lane = threadIdx.x;  // 64 = 1 wave
    int e0 = off[d], e1 = off[d + 1];
    float4 ad = *(const float4*)(adst + (size_t)d * 4);
    float den0 = 0.f, den1 = 0.f, den2 = 0.f, den3 = 0.f;
    float acc0 = 0.f, acc1 = 0.f, acc2 = 0.f, acc3 = 0.f;

    for (int base = e0; base < e1; base += 64) {
        int cnt = min(64, e1 - base);
        if (lane < cnt) {
            int s = esrc[base + lane];
            ssh[lane] = s;
            float4 as = *(const float4*)(asrc + (size_t)s * 4);
            cf[lane][0] = __expf(lrelu(as.x + ad.x));
            cf[lane][1] = __expf(lrelu(as.y + ad.y));
            cf[lane][2] = __expf(lrelu(as.z + ad.z));
            cf[lane][3] = __expf(lrelu(as.w + ad.w));
        }
        __syncthreads();
        #pragma unroll 2
        for (int i = 0; i < cnt; ++i) {
            int s = ssh[i];
            float4 c = *(const float4*)cf[i];
            den0 += c.x; den1 += c.y; den2 += c.z; den3 += c.w;
            const unsigned short* hs = hb + (size_t)s * F1;
            acc0 += c.x * bf2f(hs[lane]);
            acc1 += c.y * bf2f(hs[64 + lane]);
            acc2 += c.z * bf2f(hs[128 + lane]);
            acc3 += c.w * bf2f(hs[192 + lane]);
        }
        __syncthreads();
    }

    float r0 = 1.f / fmaxf(den0, 1e-16f);
    float r1 = 1.f / fmaxf(den1, 1e-16f);
    float r2 = 1.f / fmaxf(den2, 1e-16f);
    float r3 = 1.f / fmaxf(den3, 1e-16f);
    if (LAYER == 1) {
        float v[4] = { fmaxf(acc0 * r0 + bias[lane], 0.f),
                       fmaxf(acc1 * r1 + bias[64 + lane], 0.f),
                       fmaxf(acc2 * r2 + bias[128 + lane], 0.f),
                       fmaxf(acc3 * r3 + bias[192 + lane], 0.f) };
        #pragma unroll
        for (int hh = 0; hh < 4; ++hh) {
            unsigned short hbv = f2bf(v[hh]);
            oh[(size_t)d * F1 + hh * 64 + lane] = hbv;
            ol[(size_t)d * F1 + hh * 64 + lane] = f2bf(v[hh] - bf2f(hbv));
        }
    } else {
        outF[(size_t)d * HID + lane] =
            0.25f * (acc0 * r0 + acc1 * r1 + acc2 * r2 + acc3 * r3) + bias[lane];
    }
}

// ---------------- global mean pool: one block per graph, batch is sorted ----------------
__device__ __forceinline__ int lowerb(const int* __restrict__ a, int n, int v) {
    int lo = 0, hi = n;
    while (lo < hi) { int m = (lo + hi) >> 1; if (a[m] < v) lo = m + 1; else hi = m; }
    return lo;
}

__global__ void pool2_kernel(const float* __restrict__ h2,
                             const int* __restrict__ batch,
                             float* __restrict__ pooled) {
    __shared__ float sh[4][HID];
    int b = blockIdx.x;
    int t = threadIdx.x, w = t >> 6, c = t & 63;
    int lo = lowerb(batch, N_NODES, b);
    int hi = lowerb(batch, N_NODES, b + 1);
    float s = 0.f;
    for (int n = lo + w; n < hi; n += 4) s += h2[(size_t)n * HID + c];
    sh[w][c] = s;
    __syncthreads();
    if (w == 0) {
        float tot = sh[0][c] + sh[1][c] + sh[2][c] + sh[3][c];
        pooled[b * HID + c] = tot / fmaxf((float)(hi - lo), 1.f);
    }
}

// ---------------- graph MLP ----------------
__global__ void mlp_kernel(const float* __restrict__ pooled,
                           const float* __restrict__ Wm1, const float* __restrict__ bm1,
                           const float* __restrict__ Wm2, const float* __restrict__ bm2,
                           float* __restrict__ out) {
    __shared__ float P[NB][HID];
    __shared__ float Hh[NB][HID];
    int t = threadIdx.x;
    for (int i = t; i < NB * HID; i += 256) P[i / HID][i % HID] = pooled[i];
    __syncthreads();
    for (int i = t; i < NB * HID; i += 256) {
        int b = i / HID, c = i % HID;
        float s = bm1[c];
        for (int k = 0; k < HID; ++k) s += P[b][k] * Wm1[k * HID + c];
        Hh[b][c] = fmaxf(s, 0.f);
    }
    __syncthreads();
    if (t < NB) {
        float s = bm2[0];
        for (int k = 0; k < HID; ++k) s += Hh[t][k] * Wm2[k];
        out[t] = s;
    }
}

extern "C" void kernel_launch(void* const* d_in, const int* in_sizes, int n_in,
                              void* d_out, int out_size, void* d_ws, size_t ws_size,
                              hipStream_t stream) {
    const float* x   = (const float*)d_in[0];
    const int*   ei  = (const int*)d_in[1];
    const int*   bat = (const int*)d_in[2];
    const float* W1  = (const float*)d_in[3];
    const float* as1 = (const float*)d_in[4];
    const float* ad1 = (const float*)d_in[5];
    const float* b1  = (const float*)d_in[6];
    const float* W2  = (const float*)d_in[7];
    const float* as2 = (const float*)d_in[8];
    const float* ad2 = (const float*)d_in[9];
    const float* b2  = (const float*)d_in[10];
    const float* Wm1 = (const float*)d_in[11];
    const float* bm1 = (const float*)d_in[12];
    const float* Wm2 = (const float*)d_in[13];
    const float* bm2 = (const float*)d_in[14];
    float* out = (float*)d_out;

    char* ws = (char*)d_ws;
    size_t cursor = 0;
    auto alloc = [&](size_t bytes) {
        void* p = ws + cursor;
        cursor += (bytes + 511) & ~(size_t)511;
        return p;
    };
    int*   deg    = (int*)alloc((size_t)N_NODES * 4);
    int*   off    = (int*)alloc((size_t)(N_NODES + 1) * 4);
    int*   part   = (int*)alloc((size_t)SCAN_NBLK * 4);
    int*   esrc   = (int*)alloc((size_t)ETOT * 4);
    unsigned short* bufHb = (unsigned short*)alloc((size_t)N_NODES * F1 * 2);  // gemm bf16 out
    // union region (51.2 MB): oh/ol after agg1; bufO (agg2 out) aliases oh after gemm2
    char*  U      = (char*)alloc((size_t)N_NODES * F1 * 4);
    unsigned short* oh   = (unsigned short*)U;
    unsigned short* olsp = (unsigned short*)(U + (size_t)N_NODES * F1 * 2);
    float* bufO   = (float*)U;
    float* asrc   = (float*)alloc((size_t)N_NODES * HEADS * 4);
    float* adst   = (float*)alloc((size_t)N_NODES * HEADS * 4);
    float* pooled = (float*)alloc((size_t)NB * HID * 4);
    unsigned short* W1th = (unsigned short*)alloc((size_t)256 * IN_C * 2);
    unsigned short* W1tl = (unsigned short*)alloc((size_t)256 * IN_C * 2);
    unsigned short* W2th = (unsigned short*)alloc((size_t)256 * F1 * 2);
    unsigned short* W2tl = (unsigned short*)alloc((size_t)256 * F1 * 2);

    hipMemsetAsync(deg, 0, (size_t)N_NODES * 4, stream);

    deg_kernel<<<(ETOT + 255) / 256, 256, 0, stream>>>(ei, deg);
    scan1_kernel<<<SCAN_NBLK, 256, 0, stream>>>(deg, part);
    scan2_kernel<<<1, 256, 0, stream>>>(part, off);
    scan3_kernel<<<SCAN_NBLK, 256, 0, stream>>>(deg, part, off);
    scatter_kernel<<<(ETOT + 255) / 256, 256, 0, stream>>>(ei, off, deg, esrc);

    convw_kernel<<<(IN_C * 256 + 255) / 256, 256, 0, stream>>>(W1, W1th, W1tl, IN_C);
    convw_kernel<<<(F1 * 256 + 255) / 256, 256, 0, stream>>>(W2, W2th, W2tl, F1);

    const int GB = (N_NODES + 63) / 64;
    // layer 1 (gemm writes bf16 h + alpha_src/dst; agg gathers bf16, emits split bf16)
    gemm_mfma<true><<<GB, 256, 0, stream>>>(x, nullptr, nullptr, W1th, W1tl,
                                            as1, ad1, bufHb, asrc, adst, N_NODES, IN_C);
    agg_kernel<1><<<N_NODES, 64, 0, stream>>>(bufHb, asrc, adst, off, esrc, b1,
                                              nullptr, oh, olsp);

    // layer 2
    gemm_mfma<false><<<GB, 256, 0, stream>>>(nullptr, oh, olsp, W2th, W2tl,
                                             as2, ad2, bufHb, asrc, adst, N_NODES, F1);
    agg_kernel<2><<<N_NODES, 64, 0, stream>>>(bufHb, asrc, adst, off, esrc, b2,
                                              bufO, nullptr, nullptr);

    // pool + MLP
    pool2_kernel<<<NB, 256, 0, stream>>>(bufO, bat, pooled);
    mlp_kernel<<<1, 256, 0, stream>>>(pooled, Wm1, bm1, Wm2, bm2, out);
}